// Round 4
// baseline (850.116 us; speedup 1.0000x reference)
//
#include <hip/hip_runtime.h>

// ---------------------------------------------------------------------------
// CombinedModel: 3x relu-LSTM (keypoint) + tanh-LSTM + GRU (img) + heads.
//   GEMMs (gemm_bf): split-bf16 MFMA, BARRIER-FREE:
//     - wave-private 16 A-rows, A loaded direct to fragment layout, converted
//       hi/lo in registers (no LDS at all)
//     - B register-direct from pre-split [kt][n][32] global image
//     - vmcnt-FIFO-aware issue order: B chunks first, depth-2 A prefetch last,
//       so B-waits never drain HBM-cold A loads
//   Recurrences: block per batch row, weights in VGPRs, 4 indep FMA chains.
//   GRU: 1 wave/row, register h-seq + shuffle.
// ---------------------------------------------------------------------------

typedef short bf16x8 __attribute__((ext_vector_type(8)));
typedef float f32x4 __attribute__((ext_vector_type(4)));

__device__ __forceinline__ unsigned f2bf(float x) {
    unsigned u = __float_as_uint(x);
    return (u + 0x7FFFu + ((u >> 16) & 1u)) >> 16;   // RNE; inputs finite
}
__device__ __forceinline__ float bf2f(unsigned b) { return __uint_as_float(b << 16); }
__device__ __forceinline__ float sigmoidf_(float x) { return 1.f / (1.f + __expf(-x)); }
__device__ __forceinline__ float tanhf_(float x) {
    float e = __expf(2.f * x);
    return 1.f - 2.f / (e + 1.f);
}

// ---------------------------------------------------------------------------
// Weight pre-split: W[K,N] f32 -> bf16 hi/lo, blocked [kt][n][32].
// ---------------------------------------------------------------------------
template<int K, int N>
__device__ __forceinline__ void split_w(const float* __restrict__ W,
                                        unsigned short* __restrict__ hi,
                                        unsigned short* __restrict__ lo, int item) {
    int kt = item / N;
    int n  = item % N;
    unsigned uh[16], ul[16];
#pragma unroll
    for (int p = 0; p < 16; p++) {
        unsigned h2[2], l2[2];
#pragma unroll
        for (int e = 0; e < 2; e++) {
            int k = kt * 32 + p * 2 + e;
            float x = (k < K) ? W[(size_t)k * N + n] : 0.f;
            unsigned hb = f2bf(x);
            h2[e] = hb;
            l2[e] = f2bf(x - bf2f(hb));
        }
        uh[p] = h2[0] | (h2[1] << 16);
        ul[p] = l2[0] | (l2[1] << 16);
    }
    size_t off = (size_t)(kt * N + n) * 32;
    uint4* dh = (uint4*)(hi + off);
    uint4* dl = (uint4*)(lo + off);
#pragma unroll
    for (int c = 0; c < 4; c++) {
        uint4 v; v.x = uh[c*4]; v.y = uh[c*4+1]; v.z = uh[c*4+2]; v.w = uh[c*4+3];
        dh[c] = v;
        uint4 u; u.x = ul[c*4]; u.y = ul[c*4+1]; u.z = ul[c*4+2]; u.w = ul[c*4+3];
        dl[c] = u;
    }
}

__global__ __launch_bounds__(256) void split_all(
    const float* kW1x, const float* iWx, const float* kW2x, const float* kW3x,
    unsigned short* w1h, unsigned short* w1l, unsigned short* wih, unsigned short* wil,
    unsigned short* w2h, unsigned short* w2l, unsigned short* w3h, unsigned short* w3l) {
    int wid = blockIdx.x * 256 + threadIdx.x;
    if (wid < 13312)       split_w<1662, 256>(kW1x, w1h, w1l, wid);
    else if (wid < 29696)  split_w<2048, 256>(iWx,  wih, wil, wid - 13312);
    else if (wid < 30720)  split_w<64,   512>(kW2x, w2h, w2l, wid - 29696);
    else if (wid < 31744)  split_w<128,  256>(kW3x, w3h, w3l, wid - 30720);
}

// ---------------------------------------------------------------------------
// Barrier-free GEMM: out = A[16384,Kreal] @ W + bias.
// Block 256 thr (4 waves); tile 64 rows x 256 cols; wave w owns rows w*16..+15
// and all 256 cols (16 nt-tiles of 16x16x32, 3 split-MFMAs each).
// grid = (M/64, Nfull/256, ksplit); ks==0 partial carries bias.
// ---------------------------------------------------------------------------
__global__ __launch_bounds__(256, 2) void gemm_bf(
    const float* __restrict__ A, const unsigned short* __restrict__ Bhi,
    const unsigned short* __restrict__ Blo, const float* __restrict__ bias,
    float* __restrict__ out0, float* __restrict__ out1,
    int Kreal, int Kt, int Nfull) {
    const int m0 = blockIdx.x * 64;
    const int n0 = blockIdx.y * 256;
    const int ks = blockIdx.z;
    const int ktChunk = (Kt + gridDim.z - 1) / gridDim.z;
    const int kt0 = ks * ktChunk;
    const int ktEnd = min(Kt, kt0 + ktChunk);
    const int tid  = threadIdx.x;
    const int lane = tid & 63;
    const int wv   = tid >> 6;
    const int l15  = lane & 15;
    const int q    = lane >> 4;

    const float* arow = A + (size_t)(m0 + wv * 16 + l15) * Kreal;
    const int lp = l15 * 32 + q * 8;     // lane part of B fragment offset

    f32x4 acc[16];
#pragma unroll
    for (int i = 0; i < 16; i++) acc[i] = (f32x4){0.f, 0.f, 0.f, 0.f};

    float af[2][8];
    auto loadA = [&](int kt, float* r) {
        int kb = kt * 32 + q * 8;
#pragma unroll
        for (int j = 0; j < 4; j++) {
            int gk = kb + 2 * j;
            float x0 = 0.f, x1 = 0.f;
            if (gk + 2 <= Kreal) {
                float2 p = *(const float2*)(arow + gk);   // rows 8B-aligned
                x0 = p.x; x1 = p.y;
            } else if (gk < Kreal) {
                x0 = arow[gk];
            }
            r[2*j] = x0; r[2*j+1] = x1;
        }
    };
    union BF8 { unsigned u[4]; bf16x8 v; };
    auto conv = [&](const float* r, bf16x8& ah, bf16x8& al) {
        BF8 H, L;
#pragma unroll
        for (int p = 0; p < 4; p++) {
            unsigned h0 = f2bf(r[2*p]), h1 = f2bf(r[2*p+1]);
            unsigned l0 = f2bf(r[2*p] - bf2f(h0));
            unsigned l1 = f2bf(r[2*p+1] - bf2f(h1));
            H.u[p] = h0 | (h1 << 16);
            L.u[p] = l0 | (l1 << 16);
        }
        ah = H.v; al = L.v;
    };

    loadA(kt0, af[0]);
    if (kt0 + 1 < ktEnd) loadA(kt0 + 1, af[1]);

    bf16x8 bh[2][4], bl[2][4];
    for (int kt = kt0; kt < ktEnd; kt++) {
        const unsigned short* bhp = Bhi + (size_t)kt * Nfull * 32 + n0 * 32 + lp;
        const unsigned short* blp = Blo + (size_t)kt * Nfull * 32 + n0 * 32 + lp;
        // ---- B chunks 0,1 first (oldest in FIFO -> retire first) ----
#pragma unroll
        for (int c = 0; c < 2; c++)
#pragma unroll
            for (int i = 0; i < 4; i++) {
                bh[c][i] = *(const bf16x8*)(bhp + (c * 4 + i) * 512);
                bl[c][i] = *(const bf16x8*)(blp + (c * 4 + i) * 512);
            }
        bf16x8 ah, al;
        conv(af[(kt - kt0) & 1], ah, al);    // A loaded 2 kts ago: retired
        // ---- chunk 0 MFMA ----
#pragma unroll
        for (int i = 0; i < 4; i++) {
            acc[i] = __builtin_amdgcn_mfma_f32_16x16x32_bf16(ah, bh[0][i], acc[i], 0, 0, 0);
            acc[i] = __builtin_amdgcn_mfma_f32_16x16x32_bf16(ah, bl[0][i], acc[i], 0, 0, 0);
            acc[i] = __builtin_amdgcn_mfma_f32_16x16x32_bf16(al, bh[0][i], acc[i], 0, 0, 0);
        }
        // ---- B chunk 2 (reuses slot 0) ----
#pragma unroll
        for (int i = 0; i < 4; i++) {
            bh[0][i] = *(const bf16x8*)(bhp + (8 + i) * 512);
            bl[0][i] = *(const bf16x8*)(blp + (8 + i) * 512);
        }
        // ---- chunk 1 MFMA ----
#pragma unroll
        for (int i = 0; i < 4; i++) {
            acc[4+i] = __builtin_amdgcn_mfma_f32_16x16x32_bf16(ah, bh[1][i], acc[4+i], 0, 0, 0);
            acc[4+i] = __builtin_amdgcn_mfma_f32_16x16x32_bf16(ah, bl[1][i], acc[4+i], 0, 0, 0);
            acc[4+i] = __builtin_amdgcn_mfma_f32_16x16x32_bf16(al, bh[1][i], acc[4+i], 0, 0, 0);
        }
        // ---- B chunk 3 (reuses slot 1) ----
#pragma unroll
        for (int i = 0; i < 4; i++) {
            bh[1][i] = *(const bf16x8*)(bhp + (12 + i) * 512);
            bl[1][i] = *(const bf16x8*)(blp + (12 + i) * 512);
        }
        // ---- A prefetch depth-2, issued LAST (youngest -> never gates B) ----
        if (kt + 2 < ktEnd) loadA(kt + 2, af[(kt - kt0) & 1]);
        // ---- chunk 2 MFMA (slot 0) ----
#pragma unroll
        for (int i = 0; i < 4; i++) {
            acc[8+i] = __builtin_amdgcn_mfma_f32_16x16x32_bf16(ah, bh[0][i], acc[8+i], 0, 0, 0);
            acc[8+i] = __builtin_amdgcn_mfma_f32_16x16x32_bf16(ah, bl[0][i], acc[8+i], 0, 0, 0);
            acc[8+i] = __builtin_amdgcn_mfma_f32_16x16x32_bf16(al, bh[0][i], acc[8+i], 0, 0, 0);
        }
        // ---- chunk 3 MFMA (slot 1) ----
#pragma unroll
        for (int i = 0; i < 4; i++) {
            acc[12+i] = __builtin_amdgcn_mfma_f32_16x16x32_bf16(ah, bh[1][i], acc[12+i], 0, 0, 0);
            acc[12+i] = __builtin_amdgcn_mfma_f32_16x16x32_bf16(ah, bl[1][i], acc[12+i], 0, 0, 0);
            acc[12+i] = __builtin_amdgcn_mfma_f32_16x16x32_bf16(al, bh[1][i], acc[12+i], 0, 0, 0);
        }
    }
    // ---- epilogue: C/D col=lane&15, row=(lane>>4)*4+reg ----
    float* op = (ks == 0) ? out0 : out1;
#pragma unroll
    for (int nt = 0; nt < 16; nt++) {
        int gcol = n0 + nt * 16 + l15;
        float bv = (ks == 0) ? bias[gcol] : 0.f;
#pragma unroll
        for (int r = 0; r < 4; r++) {
            int grow = m0 + wv * 16 + q * 4 + r;
            op[(size_t)grow * Nfull + gcol] = acc[nt][r] + bv;
        }
    }
}

// ---------------------------------------------------------------------------
// LSTM H=64, G=256 (dual-config). xz = sum of two partials (p1 nullable).
// ---------------------------------------------------------------------------
__global__ __launch_bounds__(256) void lstm_h64(
    int nA,
    const float* __restrict__ xA0, const float* __restrict__ xA1,
    const float* __restrict__ WhA, float* __restrict__ hA, int actA,
    const float* __restrict__ xB0, const float* __restrict__ xB1,
    const float* __restrict__ WhB, float* __restrict__ hB, int actB) {
    int bid = blockIdx.x;
    bool sec = bid >= nA;
    int b = sec ? bid - nA : bid;
    const float* x0 = sec ? xB0 : xA0;
    const float* x1 = sec ? xB1 : xA1;
    const float* Wh = sec ? WhB : WhA;
    float* hout     = sec ? hB  : hA;
    int act         = sec ? actB : actA;
    bool has1 = (x1 != nullptr);

    int g = threadIdx.x;
    float w[64];
#pragma unroll
    for (int k = 0; k < 64; k++) w[k] = Wh[k * 256 + g];

    __shared__ alignas(16) float hs[64];
    __shared__ float za[256];
    if (g < 64) hs[g] = 0.f;
    float c = 0.f;
    __syncthreads();

    const float* x0r = x0 + (size_t)b * 64 * 256;
    const float* x1r = has1 ? x1 + (size_t)b * 64 * 256 : x0r;
    float* hr = hout + (size_t)b * 64 * 64;
    bool isc = (g >= 128) && (g < 192);
    float cur = x0r[g] + (has1 ? x1r[g] : 0.f);
    for (int t = 0; t < 64; t++) {
        float nxt = 0.f;
        if (t < 63) {
            nxt = x0r[(t + 1) * 256 + g];
            if (has1) nxt += x1r[(t + 1) * 256 + g];
        }
        float z0 = cur, z1 = 0.f, z2 = 0.f, z3 = 0.f;
#pragma unroll
        for (int kk = 0; kk < 16; kk++) {
            float4 h4 = *(const float4*)&hs[kk * 4];
            z0 = fmaf(h4.x, w[kk * 4 + 0], z0);
            z1 = fmaf(h4.y, w[kk * 4 + 1], z1);
            z2 = fmaf(h4.z, w[kk * 4 + 2], z2);
            z3 = fmaf(h4.w, w[kk * 4 + 3], z3);
        }
        float z = (z0 + z1) + (z2 + z3);
        float a;
        if (isc) a = (act == 0) ? fmaxf(z, 0.f) : tanhf_(z);
        else     a = sigmoidf_(z);
        za[g] = a;
        __syncthreads();
        if (g < 64) {
            float iv = za[g], fv = za[64 + g], cd = za[128 + g], ov = za[192 + g];
            c = fmaf(fv, c, iv * cd);
            float ca = (act == 0) ? fmaxf(c, 0.f) : tanhf_(c);
            float h = ov * ca;
            hs[g] = h;
            hr[t * 64 + g] = h;
        }
        __syncthreads();
        cur = nxt;
    }
}

// ---------------------------------------------------------------------------
// LSTM H=128, G=512 (keypoint layer 2, relu).
// ---------------------------------------------------------------------------
__global__ __launch_bounds__(512, 2) void lstm_h128(
    const float* __restrict__ xz, const float* __restrict__ Wh, float* __restrict__ hout) {
    int b = blockIdx.x;
    int g = threadIdx.x;
    float w[128];
#pragma unroll
    for (int k = 0; k < 128; k++) w[k] = Wh[k * 512 + g];

    __shared__ alignas(16) float hs[128];
    __shared__ float za[512];
    if (g < 128) hs[g] = 0.f;
    float c = 0.f;
    __syncthreads();

    const float* xzr = xz + (size_t)b * 64 * 512;
    float* hr = hout + (size_t)b * 64 * 128;
    bool isc = (g >= 256) && (g < 384);
    float cur = xzr[g];
    for (int t = 0; t < 64; t++) {
        float nxt = 0.f;
        if (t < 63) nxt = xzr[(t + 1) * 512 + g];
        float z0 = cur, z1 = 0.f, z2 = 0.f, z3 = 0.f;
#pragma unroll
        for (int kk = 0; kk < 32; kk++) {
            float4 h4 = *(const float4*)&hs[kk * 4];
            z0 = fmaf(h4.x, w[kk * 4 + 0], z0);
            z1 = fmaf(h4.y, w[kk * 4 + 1], z1);
            z2 = fmaf(h4.z, w[kk * 4 + 2], z2);
            z3 = fmaf(h4.w, w[kk * 4 + 3], z3);
        }
        float z = (z0 + z1) + (z2 + z3);
        float a = isc ? fmaxf(z, 0.f) : sigmoidf_(z);
        za[g] = a;
        __syncthreads();
        if (g < 128) {
            float iv = za[g], fv = za[128 + g], cd = za[256 + g], ov = za[384 + g];
            c = fmaf(fv, c, iv * cd);
            float h = ov * fmaxf(c, 0.f);
            hs[g] = h;
            hr[t * 128 + g] = h;
        }
        __syncthreads();
        cur = nxt;
    }
}

// ---------------------------------------------------------------------------
// GRU (reset_after), H=8, G=24. One wave per batch row, shuffle-based.
// ---------------------------------------------------------------------------
__global__ __launch_bounds__(64) void gru_kernel(
    const float* __restrict__ hsimg, const float* __restrict__ gWx,
    const float* __restrict__ gWh, const float* __restrict__ gb,
    float* __restrict__ glast) {
    int b = blockIdx.x;
    int qq = threadIdx.x;
    int col = (qq < 24) ? qq : 0;
    float wx[64], wh[8];
#pragma unroll
    for (int k = 0; k < 64; k++) wx[k] = gWx[k * 24 + col];
#pragma unroll
    for (int k = 0; k < 8; k++)  wh[k] = gWh[k * 24 + col];
    float b0 = gb[col], b1 = gb[24 + col];

    float hval = 0.f;
    const float* hb = hsimg + (size_t)b * 64 * 64;
    float cur = hb[qq];
    for (int t = 0; t < 64; t++) {
        float nxt = (t < 63) ? hb[(t + 1) * 64 + qq] : 0.f;
        float s0 = b0, s1 = 0.f, s2 = 0.f, s3 = 0.f;
#pragma unroll
        for (int k = 0; k < 64; k += 4) {
            s0 = fmaf(__shfl(cur, k + 0), wx[k + 0], s0);
            s1 = fmaf(__shfl(cur, k + 1), wx[k + 1], s1);
            s2 = fmaf(__shfl(cur, k + 2), wx[k + 2], s2);
            s3 = fmaf(__shfl(cur, k + 3), wx[k + 3], s3);
        }
        float sx = (s0 + s1) + (s2 + s3);
        float sr = b1;
#pragma unroll
        for (int k = 0; k < 8; k++) sr = fmaf(__shfl(hval, k), wh[k], sr);
        float xzz = __shfl(sx, qq),      rzz = __shfl(sr, qq);
        float xzr = __shfl(sx, 8 + qq),  rzr = __shfl(sr, 8 + qq);
        float xzh = __shfl(sx, 16 + qq), rzh = __shfl(sr, 16 + qq);
        float zz = sigmoidf_(xzz + rzz);
        float rv = sigmoidf_(xzr + rzr);
        float hc = tanhf_(xzh + rv * rzh);
        hval = zz * hval + (1.f - zz) * hc;
        cur = nxt;
    }
    if (qq < 8) glast[b * 8 + qq] = hval;
}

// ---------------------------------------------------------------------------
// Dense heads + concat + final dense + softmax. 4 blocks x 64 rows.
// ---------------------------------------------------------------------------
__global__ __launch_bounds__(64) void final_head(
    const float* __restrict__ h3seq, const float* __restrict__ glast,
    const float* __restrict__ kD1w, const float* __restrict__ kD1b,
    const float* __restrict__ kD2w, const float* __restrict__ kD2b,
    const float* __restrict__ iDw,  const float* __restrict__ iDb,
    const float* __restrict__ fW,   const float* __restrict__ fb,
    float* __restrict__ outp) {
    int b = blockIdx.x * 64 + threadIdx.x;
    float h3[64];
#pragma unroll
    for (int k = 0; k < 64; k++) h3[k] = h3seq[((size_t)b * 64 + 63) * 64 + k];
    float d1[64];
#pragma unroll
    for (int j = 0; j < 64; j++) {
        float s = kD1b[j];
#pragma unroll
        for (int k = 0; k < 64; k++) s = fmaf(h3[k], kD1w[k * 64 + j], s);
        d1[j] = fmaxf(s, 0.f);
    }
    float d2[32];
#pragma unroll
    for (int j = 0; j < 32; j++) {
        float s = kD2b[j];
#pragma unroll
        for (int k = 0; k < 64; k++) s = fmaf(d1[k], kD2w[k * 32 + j], s);
        d2[j] = fmaxf(s, 0.f);
    }
    float gi[8];
#pragma unroll
    for (int k = 0; k < 8; k++) gi[k] = glast[b * 8 + k];
    float io[8];
#pragma unroll
    for (int j = 0; j < 8; j++) {
        float s = iDb[j];
#pragma unroll
        for (int k = 0; k < 8; k++) s = fmaf(gi[k], iDw[k * 8 + j], s);
        io[j] = fmaxf(s, 0.f);
    }
    float lg[10];
#pragma unroll
    for (int j = 0; j < 10; j++) {
        float s = fb[j];
#pragma unroll
        for (int k = 0; k < 8; k++)  s = fmaf(io[k], fW[k * 10 + j], s);
#pragma unroll
        for (int k = 0; k < 32; k++) s = fmaf(d2[k], fW[(8 + k) * 10 + j], s);
        lg[j] = s;
    }
    float mx = lg[0];
#pragma unroll
    for (int j = 1; j < 10; j++) mx = fmaxf(mx, lg[j]);
    float den = 0.f, ex[10];
#pragma unroll
    for (int j = 0; j < 10; j++) { ex[j] = __expf(lg[j] - mx); den += ex[j]; }
    float inv = 1.f / den;
#pragma unroll
    for (int j = 0; j < 10; j++) outp[b * 10 + j] = ex[j] * inv;
}

// ---------------------------------------------------------------------------
extern "C" void kernel_launch(void* const* d_in, const int* in_sizes, int n_in,
                              void* d_out, int out_size, void* d_ws, size_t ws_size,
                              hipStream_t stream) {
    const float* keypoint = (const float*)d_in[0];
    const float* img      = (const float*)d_in[1];
    const float* kW1x = (const float*)d_in[2];
    const float* kW1h = (const float*)d_in[3];
    const float* kb1  = (const float*)d_in[4];
    const float* kW2x = (const float*)d_in[5];
    const float* kW2h = (const float*)d_in[6];
    const float* kb2  = (const float*)d_in[7];
    const float* kW3x = (const float*)d_in[8];
    const float* kW3h = (const float*)d_in[9];
    const float* kb3  = (const float*)d_in[10];
    const float* kD1w = (const float*)d_in[11];
    const float* kD1b = (const float*)d_in[12];
    const float* kD2w = (const float*)d_in[13];
    const float* kD2b = (const float*)d_in[14];
    const float* iWx  = (const float*)d_in[15];
    const float* iWh  = (const float*)d_in[16];
    const float* ib   = (const float*)d_in[17];
    const float* gWx  = (const float*)d_in[18];
    const float* gWh  = (const float*)d_in[19];
    const float* gb   = (const float*)d_in[20];
    const float* iDw  = (const float*)d_in[21];
    const float* iDb  = (const float*)d_in[22];
    const float* fW   = (const float*)d_in[23];
    const float* fb   = (const float*)d_in[24];
    float* outp = (float*)d_out;

    char* ws = (char*)d_ws;
    const size_t MB16 = (size_t)16384 * 256 * 4;
    float* r1a = (float*)(ws);
    float* r1b = (float*)(ws + MB16);
    float* r2a = (float*)(ws + 2 * MB16);
    float* r2b = (float*)(ws + 3 * MB16);
    size_t off = 4 * MB16;
    float* h1seq = (float*)(ws + off); off += (size_t)16384 * 64 * 4;
    float* h2seq = (float*)(ws + off); off += (size_t)16384 * 128 * 4;
    float* hsimg = (float*)(ws + off); off += (size_t)16384 * 64 * 4;
    float* glast = (float*)(ws + off); off += (size_t)256 * 8 * 4;
    unsigned short* w1h = (unsigned short*)(ws + off); off += (size_t)52 * 256 * 32 * 2;
    unsigned short* w1l = (unsigned short*)(ws + off); off += (size_t)52 * 256 * 32 * 2;
    unsigned short* wih = (unsigned short*)(ws + off); off += (size_t)64 * 256 * 32 * 2;
    unsigned short* wil = (unsigned short*)(ws + off); off += (size_t)64 * 256 * 32 * 2;
    unsigned short* w2h = (unsigned short*)(ws + off); off += (size_t)2 * 512 * 32 * 2;
    unsigned short* w2l = (unsigned short*)(ws + off); off += (size_t)2 * 512 * 32 * 2;
    unsigned short* w3h = (unsigned short*)(ws + off); off += (size_t)4 * 256 * 32 * 2;
    unsigned short* w3l = (unsigned short*)(ws + off); off += (size_t)4 * 256 * 32 * 2;
    float* xz2   = r2a;   // spans r2a+r2b after img partials consumed
    float* h3seq = h1seq;

    split_all<<<124, 256, 0, stream>>>(kW1x, iWx, kW2x, kW3x,
                                       w1h, w1l, wih, wil, w2h, w2l, w3h, w3l);
    // xz1 partials: Kt=52, ks=2 -> ktChunk 26
    gemm_bf<<<dim3(256, 1, 2), 256, 0, stream>>>(keypoint, w1h, w1l, kb1, r1a, r1b, 1662, 52, 256);
    // xz_img partials: Kt=64, ks=2 -> ktChunk 32
    gemm_bf<<<dim3(256, 1, 2), 256, 0, stream>>>(img, wih, wil, ib, r2a, r2b, 2048, 64, 256);
    lstm_h64<<<512, 256, 0, stream>>>(256, r1a, r1b, kW1h, h1seq, 0, r2a, r2b, iWh, hsimg, 1);
    // xz2: Kt=2, N=512 -> 2 n-blocks
    gemm_bf<<<dim3(256, 2, 1), 256, 0, stream>>>(h1seq, w2h, w2l, kb2, xz2, xz2, 64, 2, 512);
    lstm_h128<<<256, 512, 0, stream>>>(xz2, kW2h, h2seq);
    // xz3: Kt=4, ks=2 -> ktChunk 2
    gemm_bf<<<dim3(256, 1, 2), 256, 0, stream>>>(h2seq, w3h, w3l, kb3, r1a, r1b, 128, 4, 256);
    lstm_h64<<<256, 256, 0, stream>>>(256, r1a, r1b, kW3h, h3seq, 0, r1a, r1b, kW3h, h3seq, 0);
    gru_kernel<<<256, 64, 0, stream>>>(hsimg, gWx, gWh, gb, glast);
    final_head<<<4, 64, 0, stream>>>(h3seq, glast, kD1w, kD1b, kD2w, kD2b,
                                     iDw, iDb, fW, fb, outp);
    (void)in_sizes; (void)n_in; (void)out_size; (void)ws_size;
}